// Round 2
// baseline (242.476 us; speedup 1.0000x reference)
//
#include <hip/hip_runtime.h>
#include <math.h>

typedef __bf16 bf16_t;
typedef bf16_t bf16x4 __attribute__((ext_vector_type(4)));
typedef bf16_t bf16x8 __attribute__((ext_vector_type(8)));
typedef float  f32x4  __attribute__((ext_vector_type(4)));

#define L_SEQ 256
#define DMODEL 1024
#define NHEAD 16
#define DH 64

__device__ __forceinline__ float softplus_f(float x) {
    return (x > 20.f) ? x : log1pf(expf(x));
}

// ---------------- K0a: convert mu/var fp32 -> bf16 ----------------
__global__ __launch_bounds__(256) void convert_ab(const float* __restrict__ mu,
                                                  const float* __restrict__ var,
                                                  bf16_t* __restrict__ dmu,
                                                  bf16_t* __restrict__ dvar) {
    int gid = blockIdx.x * 256 + threadIdx.x;   // 0..131071, each handles 4 floats
    int i4 = gid * 4;                            // over 2*262144
    const float* s; bf16_t* d; int off;
    if (i4 < 262144) { s = mu;  d = dmu;  off = i4; }
    else             { s = var; d = dvar; off = i4 - 262144; }
    float4 v = *(const float4*)(s + off);
    bf16x4 o;
    o[0] = (bf16_t)v.x; o[1] = (bf16_t)v.y; o[2] = (bf16_t)v.z; o[3] = (bf16_t)v.w;
    *(bf16x4*)(d + off) = o;
}

// ---------------- K0b: transpose + convert weights: W[K][N] fp32 -> Wt[N][K] bf16 ----------------
struct TransArgs { const float* src[8]; };

__global__ __launch_bounds__(256) void transpose_w(TransArgs ta, bf16_t* __restrict__ wtbase) {
    const int kt = blockIdx.x, nt = blockIdx.y, wm = blockIdx.z;
    const float* __restrict__ W = ta.src[wm];
    bf16_t* __restrict__ Wt = wtbase + (size_t)wm * 1048576;
    __shared__ bf16_t Ts[64][72];   // [n-local][k-local], row stride 144B (16B aligned)
    const int t = threadIdx.x;
    const int r0 = t >> 4, c4 = (t & 15) * 4;
#pragma unroll
    for (int rep = 0; rep < 4; ++rep) {
        const int r = r0 + rep * 16;  // k-local
        const float4 v = *(const float4*)&W[(size_t)(kt * 64 + r) * 1024 + nt * 64 + c4];
        Ts[c4 + 0][r] = (bf16_t)v.x;
        Ts[c4 + 1][r] = (bf16_t)v.y;
        Ts[c4 + 2][r] = (bf16_t)v.z;
        Ts[c4 + 3][r] = (bf16_t)v.w;
    }
    __syncthreads();
#pragma unroll
    for (int rep = 0; rep < 2; ++rep) {
        const int chunk = t + rep * 256;      // 0..511
        const int n = chunk >> 3, kc = (chunk & 7) * 8;
        bf16x8 v = *(const bf16x8*)&Ts[n][kc];
        *(bf16x8*)&Wt[(size_t)(nt * 64 + n) * 1024 + kt * 64 + kc] = v;
    }
}

// ---------------- K1/K3: bf16 MFMA GEMM  C[256,1024] = A[256,1024] @ W  (+bias, opt softplus) ----------------
// Wt is W^T in [N][K] bf16 layout. Tile 128x128, BK=64, 256 threads (4 waves, 2x2), 4x4 MFMA tiles/wave.
struct GemmArgs {
    const bf16_t* A[6];
    const bf16_t* Wt[6];
    const float*  bias[6];
    float*        dst[6];
    int           splus[6];
};

__global__ __launch_bounds__(256) void gemm_bf16(GemmArgs args) {
    const int z = blockIdx.z;
    const bf16_t* __restrict__ A    = args.A[z];
    const bf16_t* __restrict__ Wt   = args.Wt[z];
    const float*  __restrict__ bias = args.bias[z];
    float*        __restrict__ dst  = args.dst[z];
    const int sp = args.splus[z];

    const int n_base = blockIdx.x * 128;
    const int m_base = blockIdx.y * 128;

    __shared__ bf16_t As[128 * 72];   // [m][k], row stride 72 bf16 = 144B
    __shared__ bf16_t Bs[128 * 72];   // [n][k]

    const int t = threadIdx.x;
    const int lane = t & 63;
    const int w = t >> 6;
    const int wm = (w >> 1) * 64, wn = (w & 1) * 64;
    const int fr = lane & 15;          // fragment row (m or n)
    const int fk = (lane >> 4) * 8;    // fragment k offset

    const int r = t >> 1;              // staging row 0..127
    const int half = (t & 1) * 32;     // k offset 0/32 (each thread covers 32 bf16)

    f32x4 acc[4][4] = {};

    for (int kk = 0; kk < 1024; kk += 64) {
        const bf16_t* ga = A  + (size_t)(m_base + r) * 1024 + kk + half;
        const bf16_t* gb = Wt + (size_t)(n_base + r) * 1024 + kk + half;
        bf16x8 a0 = *(const bf16x8*)(ga);
        bf16x8 a1 = *(const bf16x8*)(ga + 8);
        bf16x8 a2 = *(const bf16x8*)(ga + 16);
        bf16x8 a3 = *(const bf16x8*)(ga + 24);
        bf16x8 b0 = *(const bf16x8*)(gb);
        bf16x8 b1 = *(const bf16x8*)(gb + 8);
        bf16x8 b2 = *(const bf16x8*)(gb + 16);
        bf16x8 b3 = *(const bf16x8*)(gb + 24);
        *(bf16x8*)&As[r * 72 + half]      = a0;
        *(bf16x8*)&As[r * 72 + half + 8]  = a1;
        *(bf16x8*)&As[r * 72 + half + 16] = a2;
        *(bf16x8*)&As[r * 72 + half + 24] = a3;
        *(bf16x8*)&Bs[r * 72 + half]      = b0;
        *(bf16x8*)&Bs[r * 72 + half + 8]  = b1;
        *(bf16x8*)&Bs[r * 72 + half + 16] = b2;
        *(bf16x8*)&Bs[r * 72 + half + 24] = b3;
        __syncthreads();
#pragma unroll
        for (int kh = 0; kh < 2; ++kh) {
            bf16x8 aF[4], bF[4];
#pragma unroll
            for (int i = 0; i < 4; ++i)
                aF[i] = *(const bf16x8*)&As[(wm + i * 16 + fr) * 72 + kh * 32 + fk];
#pragma unroll
            for (int j = 0; j < 4; ++j)
                bF[j] = *(const bf16x8*)&Bs[(wn + j * 16 + fr) * 72 + kh * 32 + fk];
#pragma unroll
            for (int i = 0; i < 4; ++i)
#pragma unroll
                for (int j = 0; j < 4; ++j)
                    acc[i][j] = __builtin_amdgcn_mfma_f32_16x16x32_bf16(aF[i], bF[j], acc[i][j], 0, 0, 0);
        }
        __syncthreads();
    }

    const int orow = (lane >> 4) * 4;
#pragma unroll
    for (int i = 0; i < 4; ++i) {
#pragma unroll
        for (int j = 0; j < 4; ++j) {
            const int col = n_base + wn + j * 16 + fr;
            const float bv = bias[col];
#pragma unroll
            for (int rr = 0; rr < 4; ++rr) {
                const int row = m_base + wm + i * 16 + orow + rr;
                float v = acc[i][j][rr] + bv;
                if (sp) v = softplus_f(v);
                dst[(size_t)row * 1024 + col] = v;
            }
        }
    }
}

// ---------------- K2a: per-(l,h) features for score bilinear form ----------------
// F1=Qm^2+Qv, F2=Qm ; G1=0.5/Kv, G2n=-Km/Kv ; c(k)=sum_d Km^2/(2Kv)+0.5*log(Kv)
__global__ __launch_bounds__(64) void feat_kernel(const float* __restrict__ Qm,
                                                  const float* __restrict__ Qv,
                                                  const float* __restrict__ Km,
                                                  const float* __restrict__ Kv,
                                                  float* __restrict__ Fhat,
                                                  float* __restrict__ Ghat,
                                                  float* __restrict__ cvec) {
    const int l = blockIdx.x, h = blockIdx.y, d = threadIdx.x;
    const int idx = l * 1024 + h * 64 + d;
    const float qm = Qm[idx], qv = Qv[idx], km = Km[idx], kv = Kv[idx];
    const float g1 = 0.5f / kv;
    const float g2n = -2.0f * km * g1;   // -Km/Kv
    const int base = (h * 256 + l) * 128;
    Fhat[base + d]      = qm * qm + qv;
    Fhat[base + 64 + d] = qm;
    Ghat[base + d]      = g1;
    Ghat[base + 64 + d] = g2n;
    float cp = km * km * g1 + 0.5f * logf(kv);
#pragma unroll
    for (int off = 32; off > 0; off >>= 1) cp += __shfl_down(cp, off, 64);
    if (d == 0) cvec[h * 256 + l] = cp;
}

// ---------------- K2b: fused scores + softmax + PV, fp32 ----------------
// block = (qt, h): 16 q rows x 256 k. scores(q,k) = -0.125*(F(q)·G(k) + c(k))
__global__ __launch_bounds__(256) void attn_kernel(const float* __restrict__ Fhat,
                                                   const float* __restrict__ Ghat,
                                                   const float* __restrict__ cvec,
                                                   const float* __restrict__ Vm,
                                                   const float* __restrict__ Vv,
                                                   bf16_t* __restrict__ Omu,
                                                   bf16_t* __restrict__ Ovar) {
    const int qt = blockIdx.x, h = blockIdx.y, q0 = qt * 16;
    __shared__ float Fs[16][128];
    __shared__ float Sc[16][256];
    __shared__ float Gs[16][260];
    __shared__ float red[16][17];
    const int t = threadIdx.x;
    const int q = t >> 4, kg = t & 15;

    {   // stage F for these 16 q rows
        const float* src = Fhat + (size_t)(h * 256 + q0 + q) * 128 + kg * 8;
        float4 v0 = *(const float4*)src;
        float4 v1 = *(const float4*)(src + 4);
        *(float4*)&Fs[q][kg * 8]     = v0;
        *(float4*)&Fs[q][kg * 8 + 4] = v1;
    }

    float acc[16];
#pragma unroll
    for (int j = 0; j < 16; ++j) acc[j] = 0.f;

    for (int dc = 0; dc < 8; ++dc) {
        __syncthreads();   // also covers Fs on first iteration; protects Gs reuse after
        {   // stage Gs[dl][k=t] transposed: conflict-free scalar writes
            const float* g = Ghat + (size_t)(h * 256 + t) * 128 + dc * 16;
            float4 g0 = *(const float4*)(g);
            float4 g1 = *(const float4*)(g + 4);
            float4 g2 = *(const float4*)(g + 8);
            float4 g3 = *(const float4*)(g + 12);
            Gs[0][t] = g0.x;  Gs[1][t] = g0.y;  Gs[2][t] = g0.z;  Gs[3][t] = g0.w;
            Gs[4][t] = g1.x;  Gs[5][t] = g1.y;  Gs[6][t] = g1.z;  Gs[7][t] = g1.w;
            Gs[8][t] = g2.x;  Gs[9][t] = g2.y;  Gs[10][t] = g2.z; Gs[11][t] = g2.w;
            Gs[12][t] = g3.x; Gs[13][t] = g3.y; Gs[14][t] = g3.z; Gs[15][t] = g3.w;
        }
        __syncthreads();
#pragma unroll
        for (int dl = 0; dl < 16; ++dl) {
            const float f = Fs[q][dc * 16 + dl];
#pragma unroll
            for (int j = 0; j < 16; ++j)
                acc[j] += f * Gs[dl][kg + 16 * j];   // k strided by 16: bank-conflict-free
        }
    }

    // scores
    const float* cb = cvec + h * 256;
#pragma unroll
    for (int j = 0; j < 16; ++j) acc[j] = -0.125f * (acc[j] + cb[kg + 16 * j]);

    // softmax over k (256) per q row
    float mloc = acc[0];
#pragma unroll
    for (int j = 1; j < 16; ++j) mloc = fmaxf(mloc, acc[j]);
    red[q][kg] = mloc;
    __syncthreads();
    float m = red[q][0];
#pragma unroll
    for (int i = 1; i < 16; ++i) m = fmaxf(m, red[q][i]);
    __syncthreads();           // WAR before reusing red
    float sloc = 0.f;
#pragma unroll
    for (int j = 0; j < 16; ++j) { acc[j] = expf(acc[j] - m); sloc += acc[j]; }
    red[q][kg] = sloc;
    __syncthreads();
    float ssum = 0.f;
#pragma unroll
    for (int i = 0; i < 16; ++i) ssum += red[q][i];
    const float inv = 1.0f / ssum;
#pragma unroll
    for (int j = 0; j < 16; ++j) Sc[q][kg + 16 * j] = acc[j] * inv;
    __syncthreads();

    // PV: out_mu = attn @ Vm, out_var = attn^2 @ Vv ; thread = (q, 4 dh cols)
    const int dg = kg;
    float am[4] = {0.f, 0.f, 0.f, 0.f};
    float av[4] = {0.f, 0.f, 0.f, 0.f};
    const float* vmp = Vm + h * 64 + dg * 4;
    const float* vvp = Vv + h * 64 + dg * 4;
#pragma unroll 4
    for (int k = 0; k < 256; ++k) {
        const float a = Sc[q][k];
        const float a2 = a * a;
        const float4 vm = *(const float4*)(vmp + (size_t)k * 1024);
        const float4 vv = *(const float4*)(vvp + (size_t)k * 1024);
        am[0] += a * vm.x;  am[1] += a * vm.y;  am[2] += a * vm.z;  am[3] += a * vm.w;
        av[0] += a2 * vv.x; av[1] += a2 * vv.y; av[2] += a2 * vv.z; av[3] += a2 * vv.w;
    }
    bf16x4 om, ov;
    om[0] = (bf16_t)am[0]; om[1] = (bf16_t)am[1]; om[2] = (bf16_t)am[2]; om[3] = (bf16_t)am[3];
    ov[0] = (bf16_t)av[0]; ov[1] = (bf16_t)av[1]; ov[2] = (bf16_t)av[2]; ov[3] = (bf16_t)av[3];
    const size_t ob = (size_t)(q0 + q) * 1024 + h * 64 + dg * 4;
    *(bf16x4*)&Omu[ob]  = om;
    *(bf16x4*)&Ovar[ob] = ov;
}

// ---------------- launch ----------------
extern "C" void kernel_launch(void* const* d_in, const int* in_sizes, int n_in,
                              void* d_out, int out_size, void* d_ws, size_t ws_size,
                              hipStream_t stream) {
    const float* mu  = (const float*)d_in[0];
    const float* var = (const float*)d_in[1];

    uint8_t* ws = (uint8_t*)d_ws;
    bf16_t* Abf_mu  = (bf16_t*)(ws);                         // 512 KB
    bf16_t* Abf_var = (bf16_t*)(ws + (512u << 10));          // 512 KB
    bf16_t* WtB     = (bf16_t*)(ws + (1u << 20));            // 8 x 2 MB
    float*  Proj    = (float*)(ws + (17u << 20));            // 6 x 1 MB: Qm,Qv,Km,Kv,Vm,Vv
    float*  Fhat    = (float*)(ws + (23u << 20));            // 2 MB
    float*  Ghat    = (float*)(ws + (25u << 20));            // 2 MB
    float*  cvec    = (float*)(ws + (27u << 20));            // 16 KB
    bf16_t* Obf_mu  = (bf16_t*)(ws + (28u << 20));           // 512 KB
    bf16_t* Obf_var = (bf16_t*)(ws + (28u << 20) + (512u << 10)); // 512 KB

    // K0a: mu/var -> bf16
    convert_ab<<<512, 256, 0, stream>>>(mu, var, Abf_mu, Abf_var);

    // K0b: transpose+convert 8 weight matrices
    TransArgs ta;
    for (int i = 0; i < 8; ++i) ta.src[i] = (const float*)d_in[2 + 2 * i];
    transpose_w<<<dim3(16, 16, 8), 256, 0, stream>>>(ta, WtB);

    // K1: six projection GEMMs (order: Qm, Qv, Km, Kv, Vm, Vv)
    GemmArgs g1;
    for (int z = 0; z < 6; ++z) {
        g1.A[z]    = (z & 1) ? Abf_var : Abf_mu;
        g1.Wt[z]   = WtB + (size_t)z * 1048576;
        g1.bias[z] = (const float*)d_in[3 + 2 * z];
        g1.dst[z]  = Proj + (size_t)z * 262144;
        g1.splus[z] = (z & 1);   // softplus on var projections
    }
    gemm_bf16<<<dim3(8, 2, 6), 256, 0, stream>>>(g1);

    // K2a: features
    feat_kernel<<<dim3(256, 16), 64, 0, stream>>>(Proj,
                                                  Proj + 262144,
                                                  Proj + 2 * 262144,
                                                  Proj + 3 * 262144,
                                                  Fhat, Ghat, cvec);

    // K2b: fused attention
    attn_kernel<<<dim3(16, 16), 256, 0, stream>>>(Fhat, Ghat, cvec,
                                                  Proj + 4 * 262144,
                                                  Proj + 5 * 262144,
                                                  Obf_mu, Obf_var);

    // K3: output projections -> d_out (mu_out first, then var_out with softplus)
    GemmArgs g3;
    for (int z = 0; z < 6; ++z) {   // init all slots; only 0,1 used
        g3.A[z]    = Obf_mu;
        g3.Wt[z]   = WtB + (size_t)6 * 1048576;
        g3.bias[z] = (const float*)d_in[15];
        g3.dst[z]  = (float*)d_out;
        g3.splus[z] = 0;
    }
    g3.A[1]    = Obf_var;
    g3.Wt[1]   = WtB + (size_t)7 * 1048576;
    g3.bias[1] = (const float*)d_in[17];
    g3.dst[1]  = (float*)d_out + 262144;
    g3.splus[1] = 1;
    gemm_bf16<<<dim3(8, 2, 2), 256, 0, stream>>>(g3);
}

// Round 3
// 183.202 us; speedup vs baseline: 1.3235x; 1.3235x over previous
//
#include <hip/hip_runtime.h>
#include <math.h>

typedef __bf16 bf16_t;
typedef bf16_t bf16x4 __attribute__((ext_vector_type(4)));
typedef bf16_t bf16x8 __attribute__((ext_vector_type(8)));
typedef float  f32x4  __attribute__((ext_vector_type(4)));

__device__ __forceinline__ float softplus_f(float x) {
    return (x > 20.f) ? x : log1pf(expf(x));
}

__device__ __forceinline__ float fast_rcp(float x) {
#if __has_builtin(__builtin_amdgcn_rcpf)
    return __builtin_amdgcn_rcpf(x);
#else
    return 1.0f / x;
#endif
}

// ---------------- prep: z<8 transpose+convert weights, z==8 convert activations ----------------
struct PrepArgs { const float* src[8]; const float* mu; const float* var; };

__global__ __launch_bounds__(256) void prep_kernel(PrepArgs pa, bf16_t* __restrict__ wtbase,
                                                   bf16_t* __restrict__ dmu, bf16_t* __restrict__ dvar) {
    const int t = threadIdx.x;
    if (blockIdx.z == 8) {   // activation convert: 2 x 262144 floats, 8 per thread
        const int gid = (blockIdx.y * 16 + blockIdx.x) * 256 + t;   // 0..65535
        const float* s; bf16_t* d; int off;
        if (gid < 32768) { s = pa.mu;  d = dmu;  off = gid * 8; }
        else             { s = pa.var; d = dvar; off = (gid - 32768) * 8; }
        float4 v0 = *(const float4*)(s + off);
        float4 v1 = *(const float4*)(s + off + 4);
        bf16x8 o;
        o[0] = (bf16_t)v0.x; o[1] = (bf16_t)v0.y; o[2] = (bf16_t)v0.z; o[3] = (bf16_t)v0.w;
        o[4] = (bf16_t)v1.x; o[5] = (bf16_t)v1.y; o[6] = (bf16_t)v1.z; o[7] = (bf16_t)v1.w;
        *(bf16x8*)(d + off) = o;
        return;
    }
    const int kt = blockIdx.x, nt = blockIdx.y, wm = blockIdx.z;
    const float* __restrict__ W = pa.src[wm];
    bf16_t* __restrict__ Wt = wtbase + (size_t)wm * 1048576;
    __shared__ bf16_t Ts[64][72];
    const int r0 = t >> 4, c4 = (t & 15) * 4;
#pragma unroll
    for (int rep = 0; rep < 4; ++rep) {
        const int r = r0 + rep * 16;
        const float4 v = *(const float4*)&W[(size_t)(kt * 64 + r) * 1024 + nt * 64 + c4];
        Ts[c4 + 0][r] = (bf16_t)v.x;
        Ts[c4 + 1][r] = (bf16_t)v.y;
        Ts[c4 + 2][r] = (bf16_t)v.z;
        Ts[c4 + 3][r] = (bf16_t)v.w;
    }
    __syncthreads();
#pragma unroll
    for (int rep = 0; rep < 2; ++rep) {
        const int chunk = t + rep * 256;
        const int n = chunk >> 3, kc = (chunk & 7) * 8;
        bf16x8 v = *(const bf16x8*)&Ts[n][kc];
        *(bf16x8*)&Wt[(size_t)(nt * 64 + n) * 1024 + kt * 64 + kc] = v;
    }
}

// ---------------- gemm: 64x64 tile, intra-block split-K (wave w owns k-slice of 256) ----------------
struct GemmArgs {
    const bf16_t* A[6];
    const bf16_t* Wt[6];
    const float*  bias[6];
    float*        dst[6];
    int           splus[6];
};

__global__ __launch_bounds__(256, 2) void gemm_splitk(GemmArgs args) {
    const int z = blockIdx.z;
    const bf16_t* __restrict__ A    = args.A[z];
    const bf16_t* __restrict__ Wt   = args.Wt[z];
    const float*  __restrict__ bias = args.bias[z];
    float*        __restrict__ dst  = args.dst[z];
    const int sp = args.splus[z];

    const int n_base = blockIdx.x * 64;
    const int m_base = blockIdx.y * 64;

    __shared__ __align__(16) unsigned char smem_raw[73728];
    bf16_t* stage = (bf16_t*)smem_raw;          // per wave: As 64x72 + Bs 64x72 bf16
    float*  Cr    = (float*)smem_raw;           // reduce phase: [4][64][68] fp32

    const int t = threadIdx.x;
    const int lane = t & 63;
    const int w = t >> 6;
    bf16_t* As = stage + w * 9216;
    bf16_t* Bs = As + 4608;

    const int r8 = lane >> 3, kb = lane & 7;    // staging map
    const int fr = lane & 15, fq = lane >> 4, fk = fq * 8;

    f32x4 acc[4][4] = {};

#pragma unroll
    for (int s = 0; s < 4; ++s) {
        const int k0 = w * 256 + s * 64;
#pragma unroll
        for (int i = 0; i < 8; ++i) {
            const int row = i * 8 + r8;
            bf16x8 av = *(const bf16x8*)&A [(size_t)(m_base + row) * 1024 + k0 + kb * 8];
            bf16x8 bv = *(const bf16x8*)&Wt[(size_t)(n_base + row) * 1024 + k0 + kb * 8];
            *(bf16x8*)&As[row * 72 + kb * 8] = av;
            *(bf16x8*)&Bs[row * 72 + kb * 8] = bv;
        }
#pragma unroll
        for (int kh = 0; kh < 2; ++kh) {
            bf16x8 aF[4], bF[4];
#pragma unroll
            for (int i = 0; i < 4; ++i)
                aF[i] = *(const bf16x8*)&As[(i * 16 + fr) * 72 + kh * 32 + fk];
#pragma unroll
            for (int j = 0; j < 4; ++j)
                bF[j] = *(const bf16x8*)&Bs[(j * 16 + fr) * 72 + kh * 32 + fk];
#pragma unroll
            for (int i = 0; i < 4; ++i)
#pragma unroll
                for (int j = 0; j < 4; ++j)
                    acc[i][j] = __builtin_amdgcn_mfma_f32_16x16x32_bf16(aF[i], bF[j], acc[i][j], 0, 0, 0);
        }
    }

    __syncthreads();   // all waves done reading staging; safe to overwrite with Cr
    {
        float* Crw = Cr + w * 4352;
        const int orow = fq * 4;
#pragma unroll
        for (int i = 0; i < 4; ++i)
#pragma unroll
            for (int j = 0; j < 4; ++j)
#pragma unroll
                for (int rr = 0; rr < 4; ++rr)
                    Crw[(i * 16 + orow + rr) * 68 + j * 16 + fr] = acc[i][j][rr];
    }
    __syncthreads();

    // reduce 4 wave-partials + bias (+softplus), write fp32
    const int cc = (t & 15) * 4;
    f32x4 bv4 = *(const f32x4*)&bias[n_base + cc];
#pragma unroll
    for (int i = 0; i < 4; ++i) {
        const int row = (t >> 4) + i * 16;
        f32x4 s0 = *(const f32x4*)&Cr[0 * 4352 + row * 68 + cc];
        f32x4 s1 = *(const f32x4*)&Cr[1 * 4352 + row * 68 + cc];
        f32x4 s2 = *(const f32x4*)&Cr[2 * 4352 + row * 68 + cc];
        f32x4 s3 = *(const f32x4*)&Cr[3 * 4352 + row * 68 + cc];
        f32x4 v = (s0 + s1) + (s2 + s3) + bv4;
        if (sp) {
            v[0] = softplus_f(v[0]); v[1] = softplus_f(v[1]);
            v[2] = softplus_f(v[2]); v[3] = softplus_f(v[3]);
        }
        *(f32x4*)&dst[(size_t)(m_base + row) * 1024 + n_base + cc] = v;
    }
}

// ---------------- attn: scores + softmax + PV, F/G/c computed on the fly ----------------
__global__ __launch_bounds__(256) void attn_kernel(const float* __restrict__ Qm,
                                                   const float* __restrict__ Qv,
                                                   const float* __restrict__ Km,
                                                   const float* __restrict__ Kv,
                                                   const float* __restrict__ Vm,
                                                   const float* __restrict__ Vv,
                                                   bf16_t* __restrict__ Omu,
                                                   bf16_t* __restrict__ Ovar) {
    const int qt = blockIdx.x, h = blockIdx.y, q0 = qt * 16;
    __shared__ float Fs[16][132];
    __shared__ float Sc[16][260];
    __shared__ float Gs[16][260];
    __shared__ float red[16][17];
    __shared__ float cs[256];
    const int t = threadIdx.x;
    const int q = t >> 4, kg = t & 15;

    {   // F: F1 = Qm^2+Qv (d 0..63), F2 = Qm (d 64..127)
        const float* qmp = Qm + (size_t)(q0 + q) * 1024 + h * 64 + kg * 4;
        const float* qvp = Qv + (size_t)(q0 + q) * 1024 + h * 64 + kg * 4;
        f32x4 qm = *(const f32x4*)qmp;
        f32x4 qv = *(const f32x4*)qvp;
        *(f32x4*)&Fs[q][kg * 4]      = qm * qm + qv;
        *(f32x4*)&Fs[q][64 + kg * 4] = qm;
    }

    float acc[16];
#pragma unroll
    for (int j = 0; j < 16; ++j) acc[j] = 0.f;
    float cacc = 0.f;

    const float* kvbase = Kv + (size_t)t * 1024 + h * 64;
    const float* kmbase = Km + (size_t)t * 1024 + h * 64;

    f32x4 kvr[4], kmr[4];
#pragma unroll
    for (int c = 0; c < 4; ++c) kvr[c] = *(const f32x4*)(kvbase + c * 4);   // chunk 0: d=0..15, g1 only

    for (int dc = 0; dc < 8; ++dc) {
        const int isg2 = dc >= 4;
        float g[16];
#pragma unroll
        for (int c = 0; c < 4; ++c)
#pragma unroll
            for (int e = 0; e < 4; ++e) {
                const float kv = kvr[c][e];
                const float r = 0.5f * fast_rcp(kv);
                if (isg2) {
                    const float km = kmr[c][e];
                    g[c * 4 + e] = -2.0f * km * r;
                    cacc += km * km * r + 0.5f * __logf(kv);
                } else {
                    g[c * 4 + e] = r;
                }
            }
        __syncthreads();   // WAR: previous chunk's compute done (also covers Fs on dc=0)
#pragma unroll
        for (int dl = 0; dl < 16; ++dl) Gs[dl][t] = g[dl];
        __syncthreads();
        if (dc < 7) {   // prefetch next chunk's K rows (hidden under compute below)
            const int nd = dc + 1, d0 = (nd & 3) * 16;
#pragma unroll
            for (int c = 0; c < 4; ++c) kvr[c] = *(const f32x4*)(kvbase + d0 + c * 4);
            if (nd >= 4) {
#pragma unroll
                for (int c = 0; c < 4; ++c) kmr[c] = *(const f32x4*)(kmbase + d0 + c * 4);
            }
        }
#pragma unroll
        for (int dl = 0; dl < 16; ++dl) {
            const float f = Fs[q][dc * 16 + dl];
#pragma unroll
            for (int j = 0; j < 16; ++j)
                acc[j] += f * Gs[dl][kg + 16 * j];
        }
    }

    cs[t] = cacc;
    __syncthreads();
#pragma unroll
    for (int j = 0; j < 16; ++j) acc[j] = -0.125f * (acc[j] + cs[kg + 16 * j]);

    // softmax over k=256 per q row
    float mloc = acc[0];
#pragma unroll
    for (int j = 1; j < 16; ++j) mloc = fmaxf(mloc, acc[j]);
    red[q][kg] = mloc;
    __syncthreads();
    float m = red[q][0];
#pragma unroll
    for (int i = 1; i < 16; ++i) m = fmaxf(m, red[q][i]);
    __syncthreads();
    float sloc = 0.f;
#pragma unroll
    for (int j = 0; j < 16; ++j) { acc[j] = expf(acc[j] - m); sloc += acc[j]; }
    red[q][kg] = sloc;
    __syncthreads();
    float ssum = 0.f;
#pragma unroll
    for (int i = 0; i < 16; ++i) ssum += red[q][i];
    const float inv = 1.0f / ssum;
#pragma unroll
    for (int j = 0; j < 16; ++j) Sc[q][kg + 16 * j] = acc[j] * inv;
    __syncthreads();

    // PV: out_mu = attn @ Vm, out_var = attn^2 @ Vv
    const int dg = kg;
    float am[4] = {0.f, 0.f, 0.f, 0.f};
    float av[4] = {0.f, 0.f, 0.f, 0.f};
    const float* vmp = Vm + h * 64 + dg * 4;
    const float* vvp = Vv + h * 64 + dg * 4;
#pragma unroll 4
    for (int k = 0; k < 256; ++k) {
        const float a = Sc[q][k];
        const float a2 = a * a;
        const float4 vm = *(const float4*)(vmp + (size_t)k * 1024);
        const float4 vv = *(const float4*)(vvp + (size_t)k * 1024);
        am[0] += a * vm.x;  am[1] += a * vm.y;  am[2] += a * vm.z;  am[3] += a * vm.w;
        av[0] += a2 * vv.x; av[1] += a2 * vv.y; av[2] += a2 * vv.z; av[3] += a2 * vv.w;
    }
    bf16x4 om, ov;
    om[0] = (bf16_t)am[0]; om[1] = (bf16_t)am[1]; om[2] = (bf16_t)am[2]; om[3] = (bf16_t)am[3];
    ov[0] = (bf16_t)av[0]; ov[1] = (bf16_t)av[1]; ov[2] = (bf16_t)av[2]; ov[3] = (bf16_t)av[3];
    const size_t ob = (size_t)(q0 + q) * 1024 + h * 64 + dg * 4;
    *(bf16x4*)&Omu[ob]  = om;
    *(bf16x4*)&Ovar[ob] = ov;
}

// ---------------- launch ----------------
extern "C" void kernel_launch(void* const* d_in, const int* in_sizes, int n_in,
                              void* d_out, int out_size, void* d_ws, size_t ws_size,
                              hipStream_t stream) {
    const float* mu  = (const float*)d_in[0];
    const float* var = (const float*)d_in[1];

    uint8_t* ws = (uint8_t*)d_ws;
    bf16_t* Abf_mu  = (bf16_t*)(ws);                              // 512 KB
    bf16_t* Abf_var = (bf16_t*)(ws + (512u << 10));               // 512 KB
    bf16_t* WtB     = (bf16_t*)(ws + (1u << 20));                 // 8 x 2 MB
    float*  Proj    = (float*)(ws + (17u << 20));                 // 6 x 1 MB: Qm,Qv,Km,Kv,Vm,Vv
    bf16_t* Obf_mu  = (bf16_t*)(ws + (23u << 20));                // 512 KB
    bf16_t* Obf_var = (bf16_t*)(ws + (23u << 20) + (512u << 10)); // 512 KB

    // prep: weights transpose+convert (z 0..7) + activation convert (z=8)
    PrepArgs pa;
    for (int i = 0; i < 8; ++i) pa.src[i] = (const float*)d_in[2 + 2 * i];
    pa.mu = mu; pa.var = var;
    prep_kernel<<<dim3(16, 16, 9), 256, 0, stream>>>(pa, WtB, Abf_mu, Abf_var);

    // K1: six projection GEMMs (Qm, Qv, Km, Kv, Vm, Vv)
    GemmArgs g1;
    for (int z = 0; z < 6; ++z) {
        g1.A[z]    = (z & 1) ? Abf_var : Abf_mu;
        g1.Wt[z]   = WtB + (size_t)z * 1048576;
        g1.bias[z] = (const float*)d_in[3 + 2 * z];
        g1.dst[z]  = Proj + (size_t)z * 262144;
        g1.splus[z] = (z & 1);
    }
    gemm_splitk<<<dim3(16, 4, 6), 256, 0, stream>>>(g1);

    // attn (computes F, G, c(k) on the fly)
    attn_kernel<<<dim3(16, 16), 256, 0, stream>>>(Proj,
                                                  Proj + 262144,
                                                  Proj + 2 * 262144,
                                                  Proj + 3 * 262144,
                                                  Proj + 4 * 262144,
                                                  Proj + 5 * 262144,
                                                  Obf_mu, Obf_var);

    // K3: output projections -> d_out
    GemmArgs g3;
    for (int z = 0; z < 6; ++z) {
        g3.A[z]    = Obf_mu;
        g3.Wt[z]   = WtB + (size_t)6 * 1048576;
        g3.bias[z] = (const float*)d_in[15];
        g3.dst[z]  = (float*)d_out;
        g3.splus[z] = 0;
    }
    g3.A[1]    = Obf_var;
    g3.Wt[1]   = WtB + (size_t)7 * 1048576;
    g3.bias[1] = (const float*)d_in[17];
    g3.dst[1]  = (float*)d_out + 262144;
    g3.splus[1] = 1;
    gemm_splitk<<<dim3(16, 4, 2), 256, 0, stream>>>(g3);
}

// Round 4
// 175.226 us; speedup vs baseline: 1.3838x; 1.0455x over previous
//
#include <hip/hip_runtime.h>
#include <math.h>

typedef __bf16 bf16_t;
typedef bf16_t bf16x4 __attribute__((ext_vector_type(4)));
typedef bf16_t bf16x8 __attribute__((ext_vector_type(8)));
typedef float  f32x4  __attribute__((ext_vector_type(4)));

__device__ __forceinline__ float softplus_f(float x) {
    return (x > 20.f) ? x : log1pf(expf(x));
}

__device__ __forceinline__ float fast_rcp(float x) {
#if __has_builtin(__builtin_amdgcn_rcpf)
    return __builtin_amdgcn_rcpf(x);
#else
    return 1.0f / x;
#endif
}

// ---------------- prep: z<8 transpose+convert weights, z==8 convert activations ----------------
struct PrepArgs { const float* src[8]; const float* mu; const float* var; };

__global__ __launch_bounds__(256) void prep_kernel(PrepArgs pa, bf16_t* __restrict__ wtbase,
                                                   bf16_t* __restrict__ dmu, bf16_t* __restrict__ dvar) {
    const int t = threadIdx.x;
    if (blockIdx.z == 8) {   // activation convert: 2 x 262144 floats, 8 per thread
        const int gid = (blockIdx.y * 16 + blockIdx.x) * 256 + t;   // 0..65535
        const float* s; bf16_t* d; int off;
        if (gid < 32768) { s = pa.mu;  d = dmu;  off = gid * 8; }
        else             { s = pa.var; d = dvar; off = (gid - 32768) * 8; }
        float4 v0 = *(const float4*)(s + off);
        float4 v1 = *(const float4*)(s + off + 4);
        bf16x8 o;
        o[0] = (bf16_t)v0.x; o[1] = (bf16_t)v0.y; o[2] = (bf16_t)v0.z; o[3] = (bf16_t)v0.w;
        o[4] = (bf16_t)v1.x; o[5] = (bf16_t)v1.y; o[6] = (bf16_t)v1.z; o[7] = (bf16_t)v1.w;
        *(bf16x8*)(d + off) = o;
        return;
    }
    const int kt = blockIdx.x, nt = blockIdx.y, wm = blockIdx.z;
    const float* __restrict__ W = pa.src[wm];
    bf16_t* __restrict__ Wt = wtbase + (size_t)wm * 1048576;
    __shared__ bf16_t Ts[64][72];
    const int r0 = t >> 4, c4 = (t & 15) * 4;
#pragma unroll
    for (int rep = 0; rep < 4; ++rep) {
        const int r = r0 + rep * 16;
        const float4 v = *(const float4*)&W[(size_t)(kt * 64 + r) * 1024 + nt * 64 + c4];
        Ts[c4 + 0][r] = (bf16_t)v.x;
        Ts[c4 + 1][r] = (bf16_t)v.y;
        Ts[c4 + 2][r] = (bf16_t)v.z;
        Ts[c4 + 3][r] = (bf16_t)v.w;
    }
    __syncthreads();
#pragma unroll
    for (int rep = 0; rep < 2; ++rep) {
        const int chunk = t + rep * 256;
        const int n = chunk >> 3, kc = (chunk & 7) * 8;
        bf16x8 v = *(const bf16x8*)&Ts[n][kc];
        *(bf16x8*)&Wt[(size_t)(nt * 64 + n) * 1024 + kt * 64 + kc] = v;
    }
}

// ---------------- gemm: 64x64 tile, intra-block split-K (wave w owns k-slice of 256) ----------------
struct GemmArgs {
    const bf16_t* A[6];
    const bf16_t* Wt[6];
    const float*  bias[6];
    float*        dst[6];
    int           splus[6];
};

__global__ __launch_bounds__(256, 2) void gemm_splitk(GemmArgs args) {
    const int z = blockIdx.z;
    const bf16_t* __restrict__ A    = args.A[z];
    const bf16_t* __restrict__ Wt   = args.Wt[z];
    const float*  __restrict__ bias = args.bias[z];
    float*        __restrict__ dst  = args.dst[z];
    const int sp = args.splus[z];

    const int n_base = blockIdx.x * 64;
    const int m_base = blockIdx.y * 64;

    __shared__ __align__(16) unsigned char smem_raw[73728];
    bf16_t* stage = (bf16_t*)smem_raw;          // per wave: As 64x72 + Bs 64x72 bf16
    float*  Cr    = (float*)smem_raw;           // reduce phase: [4][64][68] fp32

    const int t = threadIdx.x;
    const int lane = t & 63;
    const int w = t >> 6;
    bf16_t* As = stage + w * 9216;
    bf16_t* Bs = As + 4608;

    const int r8 = lane >> 3, kb = lane & 7;    // staging map
    const int fr = lane & 15, fq = lane >> 4, fk = fq * 8;

    f32x4 acc[4][4] = {};

#pragma unroll
    for (int s = 0; s < 4; ++s) {
        const int k0 = w * 256 + s * 64;
#pragma unroll
        for (int i = 0; i < 8; ++i) {
            const int row = i * 8 + r8;
            bf16x8 av = *(const bf16x8*)&A [(size_t)(m_base + row) * 1024 + k0 + kb * 8];
            bf16x8 bv = *(const bf16x8*)&Wt[(size_t)(n_base + row) * 1024 + k0 + kb * 8];
            *(bf16x8*)&As[row * 72 + kb * 8] = av;
            *(bf16x8*)&Bs[row * 72 + kb * 8] = bv;
        }
#pragma unroll
        for (int kh = 0; kh < 2; ++kh) {
            bf16x8 aF[4], bF[4];
#pragma unroll
            for (int i = 0; i < 4; ++i)
                aF[i] = *(const bf16x8*)&As[(i * 16 + fr) * 72 + kh * 32 + fk];
#pragma unroll
            for (int j = 0; j < 4; ++j)
                bF[j] = *(const bf16x8*)&Bs[(j * 16 + fr) * 72 + kh * 32 + fk];
#pragma unroll
            for (int i = 0; i < 4; ++i)
#pragma unroll
                for (int j = 0; j < 4; ++j)
                    acc[i][j] = __builtin_amdgcn_mfma_f32_16x16x32_bf16(aF[i], bF[j], acc[i][j], 0, 0, 0);
        }
    }

    __syncthreads();   // all waves done reading staging; safe to overwrite with Cr
    {
        float* Crw = Cr + w * 4352;
        const int orow = fq * 4;
#pragma unroll
        for (int i = 0; i < 4; ++i)
#pragma unroll
            for (int j = 0; j < 4; ++j)
#pragma unroll
                for (int rr = 0; rr < 4; ++rr)
                    Crw[(i * 16 + orow + rr) * 68 + j * 16 + fr] = acc[i][j][rr];
    }
    __syncthreads();

    // reduce 4 wave-partials + bias (+softplus), write fp32
    const int cc = (t & 15) * 4;
    f32x4 bv4 = *(const f32x4*)&bias[n_base + cc];
#pragma unroll
    for (int i = 0; i < 4; ++i) {
        const int row = (t >> 4) + i * 16;
        f32x4 s0 = *(const f32x4*)&Cr[0 * 4352 + row * 68 + cc];
        f32x4 s1 = *(const f32x4*)&Cr[1 * 4352 + row * 68 + cc];
        f32x4 s2 = *(const f32x4*)&Cr[2 * 4352 + row * 68 + cc];
        f32x4 s3 = *(const f32x4*)&Cr[3 * 4352 + row * 68 + cc];
        f32x4 v = (s0 + s1) + (s2 + s3) + bv4;
        if (sp) {
            v[0] = softplus_f(v[0]); v[1] = softplus_f(v[1]);
            v[2] = softplus_f(v[2]); v[3] = softplus_f(v[3]);
        }
        *(f32x4*)&dst[(size_t)(m_base + row) * 1024 + n_base + cc] = v;
    }
}

// ---------------- feat: G[h][d=128][k=256] fp32 (transposed) + cvec[h][k] ----------------
// d<64: g1 = 0.5/Kv ; d>=64: g2 = -Km/Kv ; c(k) = sum_d Km^2/(2Kv) + 0.5*log(Kv)
__global__ __launch_bounds__(256) void feat_kernel(const float* __restrict__ Km,
                                                   const float* __restrict__ Kv,
                                                   float* __restrict__ G,
                                                   float* __restrict__ cvec) {
    const int h = blockIdx.x, kb = blockIdx.y;
    const int t = threadIdx.x;
    const int kx = t & 63;            // k offset within 64-block (lane)
    const int dg = t >> 6;            // wave id: 16 d each
    const int k = kb * 64 + kx;
    const float* kvp = Kv + (size_t)k * 1024 + h * 64 + dg * 16;
    const float* kmp = Km + (size_t)k * 1024 + h * 64 + dg * 16;
    float* gbase = G + (size_t)h * 32768;
    float cp = 0.f;
#pragma unroll
    for (int c = 0; c < 4; ++c) {
        f32x4 kv = *(const f32x4*)(kvp + c * 4);
        f32x4 km = *(const f32x4*)(kmp + c * 4);
#pragma unroll
        for (int e = 0; e < 4; ++e) {
            const int d = dg * 16 + c * 4 + e;
            const float r = 0.5f * fast_rcp(kv[e]);
            gbase[(size_t)d * 256 + k]        = r;                    // g1
            gbase[(size_t)(64 + d) * 256 + k] = -2.f * km[e] * r;     // g2
            cp += km[e] * km[e] * r + 0.5f * __logf(kv[e]);
        }
    }
    __shared__ float red[4][64];
    red[dg][kx] = cp;
    __syncthreads();
    if (dg == 0)
        cvec[h * 256 + k] = red[0][kx] + red[1][kx] + red[2][kx] + red[3][kx];
}

// ---------------- attn_v2: barrier-light, wave-per-q-row ----------------
__global__ __launch_bounds__(256) void attn_v2(const float* __restrict__ Qm,
                                               const float* __restrict__ Qv,
                                               const float* __restrict__ G,
                                               const float* __restrict__ cvec,
                                               const float* __restrict__ Vm,
                                               const float* __restrict__ Vv,
                                               bf16_t* __restrict__ Omu,
                                               bf16_t* __restrict__ Ovar) {
    const int qt = blockIdx.x, h = blockIdx.y;
    const int t = threadIdx.x, w = t >> 6, lane = t & 63;
    const int q = qt * 4 + w;                 // this wave's global q row

    __shared__ float Fs[4][128];
    __shared__ float Sc[4][260];

    {   // build F row: F1 = Qm^2+Qv at d=lane, F2 = Qm at d=64+lane
        const float qm = Qm[(size_t)q * 1024 + h * 64 + lane];
        const float qv = Qv[(size_t)q * 1024 + h * 64 + lane];
        Fs[w][lane]      = qm * qm + qv;
        Fs[w][64 + lane] = qm;
    }
    __syncthreads();   // cheap; guarantees Fs visible (same-wave producer/consumer anyway)

    // scores: acc[e] = sum_d F[d] * G[d][lane*4+e]  — coalesced f32x4 loads, no barriers
    f32x4 acc = {0.f, 0.f, 0.f, 0.f};
    const float* gp = G + (size_t)h * 32768 + lane * 4;
#pragma unroll 16
    for (int d = 0; d < 128; ++d) {
        f32x4 g = *(const f32x4*)(gp + (size_t)d * 256);
        acc += Fs[w][d] * g;
    }

    f32x4 c4 = *(const f32x4*)&cvec[h * 256 + lane * 4];
    f32x4 s = (acc + c4) * (-0.125f);

    // wave-level softmax over 256 k (4 per lane)
    float mloc = fmaxf(fmaxf(s[0], s[1]), fmaxf(s[2], s[3]));
#pragma unroll
    for (int off = 32; off > 0; off >>= 1)
        mloc = fmaxf(mloc, __shfl_xor(mloc, off, 64));
    s[0] = __expf(s[0] - mloc); s[1] = __expf(s[1] - mloc);
    s[2] = __expf(s[2] - mloc); s[3] = __expf(s[3] - mloc);
    float sl = (s[0] + s[1]) + (s[2] + s[3]);
#pragma unroll
    for (int off = 32; off > 0; off >>= 1)
        sl += __shfl_xor(sl, off, 64);
    const float inv = fast_rcp(sl);
    s *= inv;
    *(f32x4*)&Sc[w][lane * 4] = s;
    __syncthreads();   // same-wave ordering safety before Sc reads

    // PV: lane owns dh=lane; out_mu = sum p*Vm, out_var = sum p^2*Vv
    float am = 0.f, av = 0.f;
    const float* vmp = Vm + h * 64 + lane;
    const float* vvp = Vv + h * 64 + lane;
#pragma unroll 8
    for (int k = 0; k < 256; ++k) {
        const float p = Sc[w][k];
        am += p * vmp[(size_t)k * 1024];
        av += p * p * vvp[(size_t)k * 1024];
    }
    const size_t ob = (size_t)q * 1024 + h * 64 + lane;
    Omu[ob]  = (bf16_t)am;
    Ovar[ob] = (bf16_t)av;
}

// ---------------- launch ----------------
extern "C" void kernel_launch(void* const* d_in, const int* in_sizes, int n_in,
                              void* d_out, int out_size, void* d_ws, size_t ws_size,
                              hipStream_t stream) {
    const float* mu  = (const float*)d_in[0];
    const float* var = (const float*)d_in[1];

    uint8_t* ws = (uint8_t*)d_ws;
    bf16_t* Abf_mu  = (bf16_t*)(ws);                              // 512 KB
    bf16_t* Abf_var = (bf16_t*)(ws + (512u << 10));               // 512 KB
    bf16_t* WtB     = (bf16_t*)(ws + (1u << 20));                 // 8 x 2 MB
    float*  Proj    = (float*)(ws + (17u << 20));                 // 6 x 1 MB: Qm,Qv,Km,Kv,Vm,Vv
    bf16_t* Obf_mu  = (bf16_t*)(ws + (23u << 20));                // 512 KB
    bf16_t* Obf_var = (bf16_t*)(ws + (23u << 20) + (512u << 10)); // 512 KB
    float*  G       = (float*)(ws + (24u << 20));                 // 2 MB: [16][128][256]
    float*  cvec    = (float*)(ws + (26u << 20));                 // 16 KB

    // prep: weights transpose+convert (z 0..7) + activation convert (z=8)
    PrepArgs pa;
    for (int i = 0; i < 8; ++i) pa.src[i] = (const float*)d_in[2 + 2 * i];
    pa.mu = mu; pa.var = var;
    prep_kernel<<<dim3(16, 16, 9), 256, 0, stream>>>(pa, WtB, Abf_mu, Abf_var);

    // K1: six projection GEMMs (Qm, Qv, Km, Kv, Vm, Vv)
    GemmArgs g1;
    for (int z = 0; z < 6; ++z) {
        g1.A[z]    = (z & 1) ? Abf_var : Abf_mu;
        g1.Wt[z]   = WtB + (size_t)z * 1048576;
        g1.bias[z] = (const float*)d_in[3 + 2 * z];
        g1.dst[z]  = Proj + (size_t)z * 262144;
        g1.splus[z] = (z & 1);
    }
    gemm_splitk<<<dim3(16, 4, 6), 256, 0, stream>>>(g1);

    // feat: G (transposed) + c
    feat_kernel<<<dim3(16, 4), 256, 0, stream>>>(Proj + 2 * 262144, Proj + 3 * 262144, G, cvec);

    // attn
    attn_v2<<<dim3(64, 16), 256, 0, stream>>>(Proj,
                                              Proj + 262144,
                                              G, cvec,
                                              Proj + 4 * 262144,
                                              Proj + 5 * 262144,
                                              Obf_mu, Obf_var);

    // K3: output projections -> d_out
    GemmArgs g3;
    for (int z = 0; z < 6; ++z) {
        g3.A[z]    = Obf_mu;
        g3.Wt[z]   = WtB + (size_t)6 * 1048576;
        g3.bias[z] = (const float*)d_in[15];
        g3.dst[z]  = (float*)d_out;
        g3.splus[z] = 0;
    }
    g3.A[1]    = Obf_var;
    g3.Wt[1]   = WtB + (size_t)7 * 1048576;
    g3.bias[1] = (const float*)d_in[17];
    g3.dst[1]  = (float*)d_out + 262144;
    g3.splus[1] = 1;
    gemm_splitk<<<dim3(16, 4, 2), 256, 0, stream>>>(g3);
}

// Round 5
// 167.274 us; speedup vs baseline: 1.4496x; 1.0475x over previous
//
#include <hip/hip_runtime.h>
#include <math.h>

typedef __bf16 bf16_t;
typedef bf16_t bf16x4 __attribute__((ext_vector_type(4)));
typedef bf16_t bf16x8 __attribute__((ext_vector_type(8)));
typedef float  f32x4  __attribute__((ext_vector_type(4)));

__device__ __forceinline__ float softplus_f(float x) {
    return (x > 20.f) ? x : log1pf(expf(x));
}

__device__ __forceinline__ float fast_rcp(float x) {
#if __has_builtin(__builtin_amdgcn_rcpf)
    return __builtin_amdgcn_rcpf(x);
#else
    return 1.0f / x;
#endif
}

// ---------------- prep: z<8 transpose+convert weights, z==8 convert activations ----------------
struct PrepArgs { const float* src[8]; const float* mu; const float* var; };

__global__ __launch_bounds__(256) void prep_kernel(PrepArgs pa, bf16_t* __restrict__ wtbase,
                                                   bf16_t* __restrict__ dmu, bf16_t* __restrict__ dvar) {
    const int t = threadIdx.x;
    if (blockIdx.z == 8) {   // activation convert: 2 x 262144 floats, 8 per thread
        const int gid = (blockIdx.y * 16 + blockIdx.x) * 256 + t;   // 0..65535
        const float* s; bf16_t* d; int off;
        if (gid < 32768) { s = pa.mu;  d = dmu;  off = gid * 8; }
        else             { s = pa.var; d = dvar; off = (gid - 32768) * 8; }
        float4 v0 = *(const float4*)(s + off);
        float4 v1 = *(const float4*)(s + off + 4);
        bf16x8 o;
        o[0] = (bf16_t)v0.x; o[1] = (bf16_t)v0.y; o[2] = (bf16_t)v0.z; o[3] = (bf16_t)v0.w;
        o[4] = (bf16_t)v1.x; o[5] = (bf16_t)v1.y; o[6] = (bf16_t)v1.z; o[7] = (bf16_t)v1.w;
        *(bf16x8*)(d + off) = o;
        return;
    }
    const int kt = blockIdx.x, nt = blockIdx.y, wm = blockIdx.z;
    const float* __restrict__ W = pa.src[wm];
    bf16_t* __restrict__ Wt = wtbase + (size_t)wm * 1048576;
    __shared__ bf16_t Ts[64][72];
    const int r0 = t >> 4, c4 = (t & 15) * 4;
#pragma unroll
    for (int rep = 0; rep < 4; ++rep) {
        const int r = r0 + rep * 16;
        const float4 v = *(const float4*)&W[(size_t)(kt * 64 + r) * 1024 + nt * 64 + c4];
        Ts[c4 + 0][r] = (bf16_t)v.x;
        Ts[c4 + 1][r] = (bf16_t)v.y;
        Ts[c4 + 2][r] = (bf16_t)v.z;
        Ts[c4 + 3][r] = (bf16_t)v.w;
    }
    __syncthreads();
#pragma unroll
    for (int rep = 0; rep < 2; ++rep) {
        const int chunk = t + rep * 256;
        const int n = chunk >> 3, kc = (chunk & 7) * 8;
        bf16x8 v = *(const bf16x8*)&Ts[n][kc];
        *(bf16x8*)&Wt[(size_t)(nt * 64 + n) * 1024 + kt * 64 + kc] = v;
    }
}

// ---------------- gemm: 64x64 tile, intra-block split-K (wave w owns k-slice of 256) ----------------
struct GemmArgs {
    const bf16_t* A[6];
    const bf16_t* Wt[6];
    const float*  bias[6];
    float*        dst[6];
    int           splus[6];
};

__global__ __launch_bounds__(256, 2) void gemm_splitk(GemmArgs args) {
    const int z = blockIdx.z;
    const bf16_t* __restrict__ A    = args.A[z];
    const bf16_t* __restrict__ Wt   = args.Wt[z];
    const float*  __restrict__ bias = args.bias[z];
    float*        __restrict__ dst  = args.dst[z];
    const int sp = args.splus[z];

    const int n_base = blockIdx.x * 64;
    const int m_base = blockIdx.y * 64;

    __shared__ __align__(16) unsigned char smem_raw[73728];
    bf16_t* stage = (bf16_t*)smem_raw;          // per wave: As 64x72 + Bs 64x72 bf16
    float*  Cr    = (float*)smem_raw;           // reduce phase: [4][64][68] fp32

    const int t = threadIdx.x;
    const int lane = t & 63;
    const int w = t >> 6;
    bf16_t* As = stage + w * 9216;
    bf16_t* Bs = As + 4608;

    const int r8 = lane >> 3, kb = lane & 7;    // staging map
    const int fr = lane & 15, fq = lane >> 4, fk = fq * 8;

    f32x4 acc[4][4] = {};

#pragma unroll
    for (int s = 0; s < 4; ++s) {
        const int k0 = w * 256 + s * 64;
#pragma unroll
        for (int i = 0; i < 8; ++i) {
            const int row = i * 8 + r8;
            bf16x8 av = *(const bf16x8*)&A [(size_t)(m_base + row) * 1024 + k0 + kb * 8];
            bf16x8 bv = *(const bf16x8*)&Wt[(size_t)(n_base + row) * 1024 + k0 + kb * 8];
            *(bf16x8*)&As[row * 72 + kb * 8] = av;
            *(bf16x8*)&Bs[row * 72 + kb * 8] = bv;
        }
#pragma unroll
        for (int kh = 0; kh < 2; ++kh) {
            bf16x8 aF[4], bF[4];
#pragma unroll
            for (int i = 0; i < 4; ++i)
                aF[i] = *(const bf16x8*)&As[(i * 16 + fr) * 72 + kh * 32 + fk];
#pragma unroll
            for (int j = 0; j < 4; ++j)
                bF[j] = *(const bf16x8*)&Bs[(j * 16 + fr) * 72 + kh * 32 + fk];
#pragma unroll
            for (int i = 0; i < 4; ++i)
#pragma unroll
                for (int j = 0; j < 4; ++j)
                    acc[i][j] = __builtin_amdgcn_mfma_f32_16x16x32_bf16(aF[i], bF[j], acc[i][j], 0, 0, 0);
        }
    }

    __syncthreads();   // all waves done reading staging; safe to overwrite with Cr
    {
        float* Crw = Cr + w * 4352;
        const int orow = fq * 4;
#pragma unroll
        for (int i = 0; i < 4; ++i)
#pragma unroll
            for (int j = 0; j < 4; ++j)
#pragma unroll
                for (int rr = 0; rr < 4; ++rr)
                    Crw[(i * 16 + orow + rr) * 68 + j * 16 + fr] = acc[i][j][rr];
    }
    __syncthreads();

    // reduce 4 wave-partials + bias (+softplus), write fp32
    const int cc = (t & 15) * 4;
    f32x4 bv4 = *(const f32x4*)&bias[n_base + cc];
#pragma unroll
    for (int i = 0; i < 4; ++i) {
        const int row = (t >> 4) + i * 16;
        f32x4 s0 = *(const f32x4*)&Cr[0 * 4352 + row * 68 + cc];
        f32x4 s1 = *(const f32x4*)&Cr[1 * 4352 + row * 68 + cc];
        f32x4 s2 = *(const f32x4*)&Cr[2 * 4352 + row * 68 + cc];
        f32x4 s3 = *(const f32x4*)&Cr[3 * 4352 + row * 68 + cc];
        f32x4 v = (s0 + s1) + (s2 + s3) + bv4;
        if (sp) {
            v[0] = softplus_f(v[0]); v[1] = softplus_f(v[1]);
            v[2] = softplus_f(v[2]); v[3] = softplus_f(v[3]);
        }
        *(f32x4*)&dst[(size_t)(m_base + row) * 1024 + n_base + cc] = v;
    }
}

// ---------------- feat: G[h][d=128][k=256] fp32 (transposed) + cvec[h][k] ----------------
__global__ __launch_bounds__(256) void feat_kernel(const float* __restrict__ Km,
                                                   const float* __restrict__ Kv,
                                                   float* __restrict__ G,
                                                   float* __restrict__ cvec) {
    const int h = blockIdx.x, kb = blockIdx.y;
    const int t = threadIdx.x;
    const int kx = t & 63;
    const int dg = t >> 6;
    const int k = kb * 64 + kx;
    const float* kvp = Kv + (size_t)k * 1024 + h * 64 + dg * 16;
    const float* kmp = Km + (size_t)k * 1024 + h * 64 + dg * 16;
    float* gbase = G + (size_t)h * 32768;
    float cp = 0.f;
#pragma unroll
    for (int c = 0; c < 4; ++c) {
        f32x4 kv = *(const f32x4*)(kvp + c * 4);
        f32x4 km = *(const f32x4*)(kmp + c * 4);
#pragma unroll
        for (int e = 0; e < 4; ++e) {
            const int d = dg * 16 + c * 4 + e;
            const float r = 0.5f * fast_rcp(kv[e]);
            gbase[(size_t)d * 256 + k]        = r;                    // g1
            gbase[(size_t)(64 + d) * 256 + k] = -2.f * km[e] * r;     // g2
            cp += km[e] * km[e] * r + 0.5f * __logf(kv[e]);
        }
    }
    __shared__ float red[4][64];
    red[dg][kx] = cp;
    __syncthreads();
    if (dg == 0)
        cvec[h * 256 + k] = red[0][kx] + red[1][kx] + red[2][kx] + red[3][kx];
}

// ---------------- attn_v3: 4 q-rows per wave (4x less L2 traffic) ----------------
__global__ __launch_bounds__(128) void attn_v3(const float* __restrict__ Qm,
                                               const float* __restrict__ Qv,
                                               const float* __restrict__ G,
                                               const float* __restrict__ cvec,
                                               const float* __restrict__ Vm,
                                               const float* __restrict__ Vv,
                                               bf16_t* __restrict__ Omu,
                                               bf16_t* __restrict__ Ovar) {
    const int bq = blockIdx.x, h = blockIdx.y;   // 8 q rows per block
    const int t = threadIdx.x, w = t >> 6, lane = t & 63;
    const int q0 = bq * 8;
    const int fw = w * 4;            // wave's first local row
    const int qw = q0 + fw;          // wave's first global q row

    __shared__ float Fs[8][128];
    __shared__ float Sc[8][260];

    {   // stage F: thread t -> (row = t>>4, chunk c = t&15, d = c*4..c*4+3)
        const int r = t >> 4, c = t & 15;
        const float* qmp = Qm + (size_t)(q0 + r) * 1024 + h * 64 + c * 4;
        const float* qvp = Qv + (size_t)(q0 + r) * 1024 + h * 64 + c * 4;
        f32x4 qm = *(const f32x4*)qmp;
        f32x4 qv = *(const f32x4*)qvp;
        *(f32x4*)&Fs[r][c * 4]      = qm * qm + qv;
        *(f32x4*)&Fs[r][64 + c * 4] = qm;
    }
    __syncthreads();

    // scores: one G load feeds 4 accumulator rows (16 FMA / 16B load)
    f32x4 acc0 = {0.f,0.f,0.f,0.f}, acc1 = acc0, acc2 = acc0, acc3 = acc0;
    const float* gp = G + (size_t)h * 32768 + lane * 4;
#pragma unroll 8
    for (int d = 0; d < 128; ++d) {
        f32x4 g = *(const f32x4*)(gp + (size_t)d * 256);
        acc0 += Fs[fw + 0][d] * g;
        acc1 += Fs[fw + 1][d] * g;
        acc2 += Fs[fw + 2][d] * g;
        acc3 += Fs[fw + 3][d] * g;
    }

    const f32x4 c4 = *(const f32x4*)&cvec[h * 256 + lane * 4];
    f32x4 sr[4];
    sr[0] = (acc0 + c4) * (-0.125f);
    sr[1] = (acc1 + c4) * (-0.125f);
    sr[2] = (acc2 + c4) * (-0.125f);
    sr[3] = (acc3 + c4) * (-0.125f);

    // per-row wave softmax over 256 k (4 per lane)
#pragma unroll
    for (int r = 0; r < 4; ++r) {
        f32x4 s = sr[r];
        float mloc = fmaxf(fmaxf(s[0], s[1]), fmaxf(s[2], s[3]));
#pragma unroll
        for (int off = 32; off > 0; off >>= 1)
            mloc = fmaxf(mloc, __shfl_xor(mloc, off, 64));
        s[0] = __expf(s[0] - mloc); s[1] = __expf(s[1] - mloc);
        s[2] = __expf(s[2] - mloc); s[3] = __expf(s[3] - mloc);
        float sl = (s[0] + s[1]) + (s[2] + s[3]);
#pragma unroll
        for (int off = 32; off > 0; off >>= 1)
            sl += __shfl_xor(sl, off, 64);
        s *= fast_rcp(sl);
        *(f32x4*)&Sc[fw + r][lane * 4] = s;
    }
    __syncthreads();

    // PV: one vm/vv load pair feeds 4 rows
    float am[4] = {0.f,0.f,0.f,0.f}, av[4] = {0.f,0.f,0.f,0.f};
    const float* vmp = Vm + h * 64 + lane;
    const float* vvp = Vv + h * 64 + lane;
#pragma unroll 8
    for (int k = 0; k < 256; ++k) {
        const float vm = vmp[(size_t)k * 1024];
        const float vv = vvp[(size_t)k * 1024];
#pragma unroll
        for (int r = 0; r < 4; ++r) {
            const float p = Sc[fw + r][k];
            am[r] += p * vm;
            av[r] += p * p * vv;
        }
    }
#pragma unroll
    for (int r = 0; r < 4; ++r) {
        const size_t ob = (size_t)(qw + r) * 1024 + h * 64 + lane;
        Omu[ob]  = (bf16_t)am[r];
        Ovar[ob] = (bf16_t)av[r];
    }
}

// ---------------- launch ----------------
extern "C" void kernel_launch(void* const* d_in, const int* in_sizes, int n_in,
                              void* d_out, int out_size, void* d_ws, size_t ws_size,
                              hipStream_t stream) {
    const float* mu  = (const float*)d_in[0];
    const float* var = (const float*)d_in[1];

    uint8_t* ws = (uint8_t*)d_ws;
    bf16_t* Abf_mu  = (bf16_t*)(ws);                              // 512 KB
    bf16_t* Abf_var = (bf16_t*)(ws + (512u << 10));               // 512 KB
    bf16_t* WtB     = (bf16_t*)(ws + (1u << 20));                 // 8 x 2 MB
    float*  Proj    = (float*)(ws + (17u << 20));                 // 6 x 1 MB: Qm,Qv,Km,Kv,Vm,Vv
    bf16_t* Obf_mu  = (bf16_t*)(ws + (23u << 20));                // 512 KB
    bf16_t* Obf_var = (bf16_t*)(ws + (23u << 20) + (512u << 10)); // 512 KB
    float*  G       = (float*)(ws + (24u << 20));                 // 2 MB: [16][128][256]
    float*  cvec    = (float*)(ws + (26u << 20));                 // 16 KB

    // prep: weights transpose+convert (z 0..7) + activation convert (z=8)
    PrepArgs pa;
    for (int i = 0; i < 8; ++i) pa.src[i] = (const float*)d_in[2 + 2 * i];
    pa.mu = mu; pa.var = var;
    prep_kernel<<<dim3(16, 16, 9), 256, 0, stream>>>(pa, WtB, Abf_mu, Abf_var);

    // K1: six projection GEMMs (Qm, Qv, Km, Kv, Vm, Vv)
    GemmArgs g1;
    for (int z = 0; z < 6; ++z) {
        g1.A[z]    = (z & 1) ? Abf_var : Abf_mu;
        g1.Wt[z]   = WtB + (size_t)z * 1048576;
        g1.bias[z] = (const float*)d_in[3 + 2 * z];
        g1.dst[z]  = Proj + (size_t)z * 262144;
        g1.splus[z] = (z & 1);
    }
    gemm_splitk<<<dim3(16, 4, 6), 256, 0, stream>>>(g1);

    // feat: G (transposed) + c
    feat_kernel<<<dim3(16, 4), 256, 0, stream>>>(Proj + 2 * 262144, Proj + 3 * 262144, G, cvec);

    // attn
    attn_v3<<<dim3(32, 16), 128, 0, stream>>>(Proj,
                                              Proj + 262144,
                                              G, cvec,
                                              Proj + 4 * 262144,
                                              Proj + 5 * 262144,
                                              Obf_mu, Obf_var);

    // K3: output projections -> d_out
    GemmArgs g3;
    for (int z = 0; z < 6; ++z) {
        g3.A[z]    = Obf_mu;
        g3.Wt[z]   = WtB + (size_t)6 * 1048576;
        g3.bias[z] = (const float*)d_in[15];
        g3.dst[z]  = (float*)d_out;
        g3.splus[z] = 0;
    }
    g3.A[1]    = Obf_var;
    g3.Wt[1]   = WtB + (size_t)7 * 1048576;
    g3.bias[1] = (const float*)d_in[17];
    g3.dst[1]  = (float*)d_out + 262144;
    g3.splus[1] = 1;
    gemm_splitk<<<dim3(16, 4, 2), 256, 0, stream>>>(g3);
}